// Round 12
// baseline (58.214 us; speedup 1.0000x reference)
//
#include <hip/hip_runtime.h>
#include <hip/hip_bf16.h>

typedef __bf16 bf16x8 __attribute__((ext_vector_type(8)));
typedef float  f32x4  __attribute__((ext_vector_type(4)));
typedef unsigned short u16;
typedef unsigned int   u32;

__device__ __forceinline__ u16 f2b(float x) {
  __bf16 b = (__bf16)x;
  return __builtin_bit_cast(u16, b);
}

__device__ __forceinline__ void gload_lds16(const u16* g, u16* l) {
  __builtin_amdgcn_global_load_lds(
      (const __attribute__((address_space(1))) void*)g,
      (__attribute__((address_space(3))) void*)l, 16, 0, 0);
}

// pack 8 f32 -> 8 bf16, one ds_write_b128
__device__ __forceinline__ void cvt8_store(u16* dst, float4 a, float4 b) {
  union { u16 u[8]; uint4 v; } r;
  r.u[0] = f2b(a.x); r.u[1] = f2b(a.y); r.u[2] = f2b(a.z); r.u[3] = f2b(a.w);
  r.u[4] = f2b(b.x); r.u[5] = f2b(b.y); r.u[6] = f2b(b.z); r.u[7] = f2b(b.w);
  *(uint4*)dst = r.v;
}

// ---- vectorized 32x128 transpose tile: W f32 [r0..r0+32)[c0..c0+128) -> T bf16 [c][r]
// float4 loads (16B/lane), LDS pitch 132 (aligned f4 writes; column reads 2-way),
// 2x uint4 stores (32B contiguous per thread). 256 tiles per 1024^2 matrix.
__device__ __forceinline__ void wtile_transpose_v2(
    const float* __restrict__ W, u16* __restrict__ T, int rem, float* tile /*32x132*/)
{
  const int t = threadIdx.x;
  const int r0 = (rem >> 3) << 5, c0 = (rem & 7) << 7;
  const int r = t >> 3, f40 = (t & 7) << 2;
  const float4* src = (const float4*)(W + (size_t)(r0 + r) * 1024 + c0);
#pragma unroll
  for (int i = 0; i < 4; ++i)
    *(float4*)&tile[r * 132 + ((f40 + i) << 2)] = src[f40 + i];
  __syncthreads();
  const int c = t >> 1, rh = (t & 1) << 4;
  union { u16 u[16]; uint4 v[2]; } o;
#pragma unroll
  for (int i = 0; i < 16; ++i)
    o.u[i] = f2b(tile[(rh + i) * 132 + c]);
  uint4* dst = (uint4*)(T + (size_t)(c0 + c) * 1024 + r0 + rh);
  dst[0] = o.v[0];
  dst[1] = o.v[1];
}

// ---------------- prep: transpose + cvt Wq/Wk/Wv (768 blocks) ----------------
__global__ __launch_bounds__(256) void prep_kernel(
    const float* __restrict__ W0, const float* __restrict__ W1,
    const float* __restrict__ W2,
    u16* __restrict__ T0, u16* __restrict__ T1, u16* __restrict__ T2)
{
  __shared__ float tile[32 * 132];
  int t = blockIdx.x;
  int z = t >> 8, rem = t & 255;
  const float* W = (z == 0) ? W0 : (z == 1) ? W1 : W2;
  u16* T = (z == 0) ? T0 : (z == 1) ? T1 : T2;
  wtile_transpose_v2(W, T, rem, tile);
}

// ---------------- shared GEMM pieces (R3-proven 128x128, 4 waves) ------------
__device__ __forceinline__ void compute_step(
    const u16* asc, const u16* bsc, int lane, int wm, int wn, f32x4 (&acc)[4][4])
{
#pragma unroll
  for (int kk = 0; kk < 2; ++kk) {
    bf16x8 af[4], bfr[4];
    int colb = (kk << 6) + ((lane >> 4) << 4);
#pragma unroll
    for (int m = 0; m < 4; ++m) {
      int r = (wm << 6) + (m << 4) + (lane & 15);
      af[m] = *(const bf16x8*)((const char*)asc + (r << 7) + (colb ^ ((r & 7) << 4)));
    }
#pragma unroll
    for (int n = 0; n < 4; ++n) {
      int r = (wn << 6) + (n << 4) + (lane & 15);
      bfr[n] = *(const bf16x8*)((const char*)bsc + (r << 7) + (colb ^ ((r & 7) << 4)));
    }
#pragma unroll
    for (int m = 0; m < 4; ++m)
#pragma unroll
      for (int n = 0; n < 4; ++n)
        acc[m][n] = __builtin_amdgcn_mfma_f32_16x16x32_bf16(af[m], bfr[n], acc[m][n], 0, 0, 0);
  }
}

__device__ __forceinline__ void stage_b(const u16* gB, u16* bs, int wave, int K, int k0) {
#pragma unroll
  for (int i = 0; i < 4; ++i) {
    int rb = (wave << 5) + (i << 3);
    gload_lds16(gB + (size_t)(i << 3) * K + k0, bs + (rb << 6));
  }
}

template <int OUTF32>
__device__ __forceinline__ void cwrite(
    void* C, int N, int row0, int col0, int lane, int wm, int wn, f32x4 (&acc)[4][4])
{
  const int crow = (lane >> 4) << 2;
  const int ccol = lane & 15;
#pragma unroll
  for (int m = 0; m < 4; ++m) {
#pragma unroll
    for (int n = 0; n < 4; ++n) {
      int r = row0 + (wm << 6) + (m << 4) + crow;
      int c = col0 + (wn << 6) + (n << 4) + ccol;
#pragma unroll
      for (int reg = 0; reg < 4; ++reg) {
        if (OUTF32) ((float*)C)[(size_t)(r + reg) * N + c] = acc[m][n][reg];
        else        ((u16*)C)[(size_t)(r + reg) * N + c] = f2b(acc[m][n][reg]);
      }
    }
  }
}

// ---------------- GEMM core, bf16 A via gload_lds (outproj) -----------------
template <int OUTF32>
__device__ __forceinline__ void gemm_core(
    const u16* __restrict__ A, const u16* __restrict__ Bt, void* __restrict__ C,
    int N, int K, int row0, int col0,
    u16* As0, u16* As1, u16* Bs0, u16* Bs1)
{
  const int tid = threadIdx.x;
  const int wave = tid >> 6, lane = tid & 63;
  const int wm = wave >> 1, wn = wave & 1;
  f32x4 acc[4][4] = {};

  const int srow = lane >> 3, sslot = lane & 7;
  const int scol = ((sslot ^ srow) << 3);
  const u16* gA = A + (size_t)(row0 + (wave << 5) + srow) * K + scol;
  const u16* gB = Bt + (size_t)(col0 + (wave << 5) + srow) * K + scol;

  stage_b(gA, As0, wave, K, 0);
  stage_b(gB, Bs0, wave, K, 0);
  __syncthreads();

  u16 *asc = As0, *bsc = Bs0, *asn = As1, *bsn = Bs1;
  for (int k0 = 0; k0 < K; k0 += 64) {
    if (k0 + 64 < K) {
      stage_b(gA, asn, wave, K, k0 + 64);
      stage_b(gB, bsn, wave, K, k0 + 64);
    }
    compute_step(asc, bsc, lane, wm, wn, acc);
    __syncthreads();
    u16* t_;
    t_ = asc; asc = asn; asn = t_;
    t_ = bsc; bsc = bsn; bsn = t_;
  }
  cwrite<OUTF32>(C, N, row0, col0, lane, wm, wn, acc);
}

// ---------------- GEMM core, f32 A reg-staged + cvt (projections, R8 exact) --
__device__ __forceinline__ void gemm_core_f32a(
    const float* __restrict__ Af,
    const u16* __restrict__ Bt, u16* __restrict__ C,
    int N, int K, int row0, int col0,
    u16* As0, u16* As1, u16* Bs0, u16* Bs1)
{
  const int tid = threadIdx.x;
  const int wave = tid >> 6, lane = tid & 63;
  const int wm = wave >> 1, wn = wave & 1;
  f32x4 acc[4][4] = {};

  const int srow = lane >> 3, sslot = lane & 7;
  const int scol = ((sslot ^ srow) << 3);
  const float* gAf = Af + (size_t)((wave << 5) + srow) * K + scol;
  const u16*  gB  = Bt + (size_t)(col0 + (wave << 5) + srow) * K + scol;
  const int awbase = (lane << 3);

  float4 a0[4], a1[4];
#pragma unroll
  for (int i = 0; i < 4; ++i) {
    const float* g = gAf + (size_t)(i << 3) * K;
    a0[i] = *(const float4*)g; a1[i] = *(const float4*)(g + 4);
  }
  stage_b(gB, Bs0, wave, K, 0);
#pragma unroll
  for (int i = 0; i < 4; ++i)
    cvt8_store(As0 + (((wave << 5) + (i << 3)) << 6) + awbase, a0[i], a1[i]);
  __syncthreads();

  u16 *asc = As0, *bsc = Bs0, *asn = As1, *bsn = Bs1;
  for (int k0 = 0; k0 < K; k0 += 64) {
    const bool more = (k0 + 64) < K;
    if (more) {
#pragma unroll
      for (int i = 0; i < 4; ++i) {
        const float* g = gAf + (size_t)(i << 3) * K + (k0 + 64);
        a0[i] = *(const float4*)g; a1[i] = *(const float4*)(g + 4);
      }
      stage_b(gB, bsn, wave, K, k0 + 64);
    }
    compute_step(asc, bsc, lane, wm, wn, acc);
    __syncthreads();
    if (more) {
#pragma unroll
      for (int i = 0; i < 4; ++i)
        cvt8_store(asn + (((wave << 5) + (i << 3)) << 6) + awbase, a0[i], a1[i]);
    }
    __syncthreads();
    u16* t_;
    t_ = asc; asc = asn; asn = t_;
    t_ = bsc; bsc = bsn; bsn = t_;
  }
  cwrite<0>(C, N, row0, col0, lane, wm, wn, acc);
}

// out projection (f32 out), 256 blocks, XCD-swizzled
template <int OUTF32>
__global__ __launch_bounds__(256, 2) void gemm_bt_kernel(
    const u16* __restrict__ A, const u16* __restrict__ Bt, void* __restrict__ C,
    int M, int N, int K)
{
  __shared__ u16 As[2][8192];
  __shared__ u16 Bs[2][8192];
  int bid = blockIdx.x;
  int t = (bid & 7) * 32 + (bid >> 3);
  const int bx = t & 7, by = t >> 3;
  gemm_core<OUTF32>(A, Bt, C, N, K, by << 7, bx << 7, As[0], As[1], Bs[0], Bs[1]);
}

// fused Q + K + V projections (384 GEMM blocks) + 256 Wo-transpose tail blocks
__global__ __launch_bounds__(256, 2) void proj_kernel(
    const float* __restrict__ q, const float* __restrict__ k, const float* __restrict__ v,
    const u16* __restrict__ Wqt, const u16* __restrict__ Wkt, const u16* __restrict__ Wvt,
    u16* __restrict__ Qp, u16* __restrict__ KVp,
    const float* __restrict__ W3, u16* __restrict__ T3)
{
  __shared__ u16 As[2][8192];
  __shared__ u16 Bs[2][8192];
  int bid = blockIdx.x;
  if (bid >= 384) {                  // Wo transpose tile (consumed by later outproj)
    wtile_transpose_v2(W3, T3, bid - 384, (float*)As);
    return;
  }
  int t = (bid & 7) * 48 + (bid >> 3);      // bijective XCD chunk (384 = 8*48)
  const float* Af; const u16* Bt; u16* C; int row0, col0;
  if (t < 256) {
    row0 = (t >> 3) << 7; col0 = (t & 7) << 7;
    Af = q + (size_t)row0 * 1024; Bt = Wqt; C = Qp;
  } else {
    int t2 = t - 256;
    row0 = (t2 >> 3) << 7; col0 = (t2 & 7) << 7;
    if (row0 < 1024) { Af = k + (size_t)row0 * 1024; Bt = Wkt; }
    else             { Af = v + (size_t)(row0 - 1024) * 1024; Bt = Wvt; }
    C = KVp;
  }
  gemm_core_f32a(Af, Bt, C, 1024, 1024, row0, col0, As[0], As[1], Bs[0], Bs[1]);
}

// ---------------- strided-local attention: 128 queries / block (R11) ---------
#define VTP2 88   // Vt pitch
#define PLP2 72   // Pl pitch
__global__ __launch_bounds__(256) void attn_kernel(
    const u16* __restrict__ Qp, const u16* __restrict__ Kp,
    const u16* __restrict__ Vp, u16* __restrict__ Ob)
{
  __shared__ u16 Ql[128 * 64];
  __shared__ u16 Kl[80 * 64];
  __shared__ u16 Vt[64 * VTP2];
  __shared__ u16 Pl[128 * PLP2];

  const int bid = blockIdx.x;
  const int t = (bid & 7) * 64 + (bid >> 3);   // bijective XCD chunk (512 = 8*64)
  const int jt2 = t & 15, h = (t >> 4) & 15, b = t >> 8;
  const int j0 = jt2 << 7;
  const int kbase = (j0 - 124) >> 2;
  const int tid = threadIdx.x;
  const int wave = tid >> 6, lane = tid & 63;

  const int srow = lane >> 3, sslot = lane & 7;
  const int scol = ((sslot ^ srow) << 3);
  for (int g = wave; g < 16; g += 4) {
    int r = (g << 3) + srow;
    const u16* ga = Qp + (((size_t)(b * 2048 + j0 + r)) << 10) + (h << 6) + scol;
    gload_lds16(ga, &Ql[g << 9]);
  }
  for (int g = wave; g < 10; g += 4) {
    int r = (g << 3) + srow;
    int key = kbase + r;
    key = key < 0 ? 0 : (key > 511 ? 511 : key);
    const u16* gk = Kp + (((size_t)(b * 512 + key)) << 10) + (h << 6) + scol;
    gload_lds16(gk, &Kl[g << 9]);
  }
  for (int idx = tid; idx < 64 * 8; idx += 256) {
    int row = idx >> 3, seg = idx & 7;
    int key = kbase + row;
    key = key < 0 ? 0 : (key > 511 ? 511 : key);
    uint4 x = *(const uint4*)(Vp + (((size_t)(b * 512 + key)) << 10) + (h << 6) + (seg << 3));
    int d0 = seg << 3;
    Vt[(d0 + 0) * VTP2 + row] = (u16)(x.x);
    Vt[(d0 + 1) * VTP2 + row] = (u16)(x.x >> 16);
    Vt[(d0 + 2) * VTP2 + row] = (u16)(x.y);
    Vt[(d0 + 3) * VTP2 + row] = (u16)(x.y >> 16);
    Vt[(d0 + 4) * VTP2 + row] = (u16)(x.z);
    Vt[(d0 + 5) * VTP2 + row] = (u16)(x.z >> 16);
    Vt[(d0 + 6) * VTP2 + row] = (u16)(x.w);
    Vt[(d0 + 7) * VTP2 + row] = (u16)(x.w >> 16);
  }
  if (tid < 128) {
    int row = tid >> 1, qd = tid & 1;
    *(uint4*)&Vt[row * VTP2 + 64 + (qd << 3)] = make_uint4(0, 0, 0, 0);
  }
  __syncthreads();

  const int s = wave >> 1;
  const int cb0 = lane & 15;
  const int frow0 = (wave << 5) + (lane & 15);

  f32x4 sacc[2][4] = {};
#pragma unroll
  for (int kk = 0; kk < 2; ++kk) {
    int colb = (kk << 6) + ((lane >> 4) << 4);
    bf16x8 aq[2];
#pragma unroll
    for (int mi = 0; mi < 2; ++mi) {
      int fr = frow0 + (mi << 4);
      aq[mi] = *(const bf16x8*)((const char*)Ql + (fr << 7) + (colb ^ ((fr & 7) << 4)));
    }
#pragma unroll
    for (int nt = 0; nt < 4; ++nt) {
      int rk = (s << 4) + (nt << 4) + (lane & 15);
      bf16x8 bk = *(const bf16x8*)((const char*)Kl + (rk << 7) + (colb ^ ((rk & 7) << 4)));
#pragma unroll
      for (int mi = 0; mi < 2; ++mi)
        sacc[mi][nt] = __builtin_amdgcn_mfma_f32_16x16x32_bf16(aq[mi], bk, sacc[mi][nt], 0, 0, 0);
    }
  }

#pragma unroll
  for (int mi = 0; mi < 2; ++mi) {
    const int rof = ((wave & 1) << 3) + (mi << 2) + (lane >> 4);
    bool vld[4]; float sc[4][4];
#pragma unroll
    for (int nt = 0; nt < 4; ++nt) {
      int c = (nt << 4) + cb0;
      vld[nt] = ((unsigned)(c - rof) < 32u) && (kbase + (s << 4) + c >= 0);
#pragma unroll
      for (int r = 0; r < 4; ++r) sc[nt][r] = sacc[mi][nt][r] * 0.125f;
    }
#pragma unroll
    for (int r = 0; r < 4; ++r) {
      float m = -3.0e38f;
#pragma unroll
      for (int nt = 0; nt < 4; ++nt) m = vld[nt] ? fmaxf(m, sc[nt][r]) : m;
      m = fmaxf(m, __shfl_xor(m, 1));
      m = fmaxf(m, __shfl_xor(m, 2));
      m = fmaxf(m, __shfl_xor(m, 4));
      m = fmaxf(m, __shfl_xor(m, 8));
      float ssum = 0.f;
      float e[4];
#pragma unroll
      for (int nt = 0; nt < 4; ++nt) {
        e[nt] = vld[nt] ? __expf(sc[nt][r] - m) : 0.f;
        ssum += e[nt];
      }
      ssum += __shfl_xor(ssum, 1);
      ssum += __shfl_xor(ssum, 2);
      ssum += __shfl_xor(ssum, 4);
      ssum += __shfl_xor(ssum, 8);
      float rs = 1.f / ssum;
      int jq = (wave << 5) + (mi << 4) + ((lane >> 4) << 2) + r;
#pragma unroll
      for (int nt = 0; nt < 4; ++nt)
        Pl[jq * PLP2 + (nt << 4) + cb0] = f2b(e[nt] * rs);
    }
  }
  __syncthreads();

  f32x4 oacc[2][4] = {};
#pragma unroll
  for (int kk = 0; kk < 2; ++kk) {
    int koff = (kk << 5) + ((lane >> 4) << 3);
    bf16x8 ap[2];
#pragma unroll
    for (int mi = 0; mi < 2; ++mi)
      ap[mi] = *(const bf16x8*)&Pl[(frow0 + (mi << 4)) * PLP2 + koff];
#pragma unroll
    for (int nt = 0; nt < 4; ++nt) {
      int dr = (nt << 4) + (lane & 15);
      bf16x8 bv = *(const bf16x8*)&Vt[dr * VTP2 + (s << 4) + koff];
#pragma unroll
      for (int mi = 0; mi < 2; ++mi)
        oacc[mi][nt] = __builtin_amdgcn_mfma_f32_16x16x32_bf16(ap[mi], bv, oacc[mi][nt], 0, 0, 0);
    }
  }

#pragma unroll
  for (int mi = 0; mi < 2; ++mi)
#pragma unroll
    for (int nt = 0; nt < 4; ++nt) {
      int d = (nt << 4) + (lane & 15);
#pragma unroll
      for (int r = 0; r < 4; ++r) {
        int jq = (wave << 5) + (mi << 4) + ((lane >> 4) << 2) + r;
        Ob[(((size_t)(b * 2048 + j0 + jq)) << 10) + (h << 6) + d] = f2b(oacc[mi][nt][r]);
      }
    }
}

extern "C" void kernel_launch(void* const* d_in, const int* in_sizes, int n_in,
                              void* d_out, int out_size, void* d_ws, size_t ws_size,
                              hipStream_t stream) {
  const float* q  = (const float*)d_in[0];
  const float* k  = (const float*)d_in[1];
  const float* v  = (const float*)d_in[2];
  const float* Wq = (const float*)d_in[3];
  const float* Wk = (const float*)d_in[4];
  const float* Wv = (const float*)d_in[5];
  const float* Wo = (const float*)d_in[6];

  char* ws = (char*)d_ws;
  const size_t MB = 1u << 20;
  u16* Wqt = (u16*)(ws + 0 * MB);    // 2 MB
  u16* Wkt = (u16*)(ws + 2 * MB);
  u16* Wvt = (u16*)(ws + 4 * MB);
  u16* Wot = (u16*)(ws + 6 * MB);
  u16* Qp  = (u16*)(ws + 8 * MB);    // 8 MB
  u16* Kp  = (u16*)(ws + 16 * MB);   // 2 MB  (Kp||Vp contiguous)
  u16* Vp  = (u16*)(ws + 18 * MB);   // 2 MB
  u16* Ob  = (u16*)(ws + 20 * MB);   // 8 MB  (total 28 MB)

  // 1) prep: transpose/convert Wq, Wk, Wv (vectorized 32x128 tiles)
  prep_kernel<<<768, 256, 0, stream>>>(Wq, Wk, Wv, Wqt, Wkt, Wvt);
  // 2) projections (f32 A direct) + vectorized Wo-transpose tail blocks
  proj_kernel<<<640, 256, 0, stream>>>(q, k, v, Wqt, Wkt, Wvt, Qp, Kp, Wo, Wot);
  // 3) attention: 128 queries/block, shared K/V window, XCD-swizzled
  attn_kernel<<<512, 256, 0, stream>>>(Qp, Kp, Vp, Ob);
  // 4) output projection (f32 out)
  gemm_bt_kernel<1><<<256, 256, 0, stream>>>(Ob, Wot, d_out, 4096, 1024, 1024);
}